// Round 1
// baseline (510.838 us; speedup 1.0000x reference)
//
#include <hip/hip_runtime.h>
#include <hip/hip_bf16.h>

typedef unsigned short ushort_t;
typedef __attribute__((ext_vector_type(8))) short short8;
typedef __attribute__((ext_vector_type(4))) short short4v;
typedef __attribute__((ext_vector_type(4))) float floatx4;

#define MFMA16(a, b, c) __builtin_amdgcn_mfma_f32_16x16x32_bf16(a, b, c, 0, 0, 0)

__device__ __forceinline__ float bf2f(ushort_t u) {
    unsigned int v = ((unsigned int)u) << 16;
    return __int_as_float((int)v);
}
__device__ __forceinline__ ushort_t f2bf(float f) {
    unsigned int x = (unsigned int)__float_as_int(f);
    unsigned int r = (x + 0x7FFFu + ((x >> 16) & 1u)) >> 16;
    return (ushort_t)r;
}
__device__ __forceinline__ floatx4 fma4(float a, floatx4 b, floatx4 c) {
    c[0] = fmaf(a, b[0], c[0]);
    c[1] = fmaf(a, b[1], c[1]);
    c[2] = fmaf(a, b[2], c[2]);
    c[3] = fmaf(a, b[3], c[3]);
    return c;
}

// ---------------------------------------------------------------- fp32 -> bf16 convert
__global__ __launch_bounds__(256) void k_cvt(const floatx4* __restrict__ src,
                                             short4v* __restrict__ dst, int n4) {
    int i = blockIdx.x * 256 + threadIdx.x;
    if (i < n4) {
        floatx4 v = src[i];
        short4v o;
        o[0] = (short)f2bf(v[0]);
        o[1] = (short)f2bf(v[1]);
        o[2] = (short)f2bf(v[2]);
        o[3] = (short)f2bf(v[3]);
        dst[i] = o;
    }
}

// ---------------------------------------------------------------- fp32 transpose -> bf16
__global__ __launch_bounds__(256) void k_transpose_cvt(const float* __restrict__ src,
                                                       ushort_t* __restrict__ dst, int R, int C) {
    __shared__ float t[32][33];
    int tx = threadIdx.x & 31, ty = threadIdx.x >> 5;
    int r0 = blockIdx.y * 32, c0 = blockIdx.x * 32;
    for (int y = ty; y < 32; y += 8) t[y][tx] = src[(r0 + y) * C + c0 + tx];
    __syncthreads();
    for (int y = ty; y < 32; y += 8) dst[(c0 + y) * R + r0 + tx] = f2bf(t[tx][y]);
}

// ---------------------------------------------------------------- K1: qkv = x @ w_qkv, scatter q/k/vT
__global__ __launch_bounds__(256) void k_qkv(const ushort_t* __restrict__ x,
                                             const ushort_t* __restrict__ wt,
                                             ushort_t* __restrict__ qs,
                                             ushort_t* __restrict__ ks,
                                             ushort_t* __restrict__ vt) {
    __shared__ __align__(16) ushort_t st[64 * 72];
    const int tid = threadIdx.x, lane = tid & 63, wv = tid >> 6;
    const int col = lane & 15, quad = lane >> 4;
    const int row0 = blockIdx.y * 64 + (wv >> 1) * 32;
    const int c0 = blockIdx.x * 64 + (wv & 1) * 32;
    const int which = blockIdx.x >> 3, hh = blockIdx.x & 7;
    const int brow0 = blockIdx.y * 64;
    const int bb = brow0 >> 11, n0 = brow0 & 2047;
    const int hidx = bb * 8 + hh;
    floatx4 acc[2][2];
#pragma unroll
    for (int i = 0; i < 2; i++)
#pragma unroll
        for (int j = 0; j < 2; j++) acc[i][j] = (floatx4){0.f, 0.f, 0.f, 0.f};
    for (int k0 = 0; k0 < 512; k0 += 32) {
        const int ko = k0 + quad * 8;
        short8 a0 = *(const short8*)&x[(row0 + col) * 512 + ko];
        short8 a1 = *(const short8*)&x[(row0 + 16 + col) * 512 + ko];
        short8 b0 = *(const short8*)&wt[(c0 + col) * 512 + ko];
        short8 b1 = *(const short8*)&wt[(c0 + 16 + col) * 512 + ko];
        acc[0][0] = MFMA16(a0, b0, acc[0][0]);
        acc[0][1] = MFMA16(a0, b1, acc[0][1]);
        acc[1][0] = MFMA16(a1, b0, acc[1][0]);
        acc[1][1] = MFMA16(a1, b1, acc[1][1]);
    }
    const float qscale = (which == 0) ? 0.125f : 1.0f;  // fold SCALE into q
#pragma unroll
    for (int i = 0; i < 2; i++)
#pragma unroll
        for (int j = 0; j < 2; j++)
#pragma unroll
            for (int r = 0; r < 4; r++) {
                int il = (wv >> 1) * 32 + i * 16 + quad * 4 + r;
                int cl = (wv & 1) * 32 + j * 16 + col;
                ushort_t hv = f2bf(acc[i][j][r] * qscale);
                if (which == 2) st[cl * 72 + il] = hv;   // transposed: [d][n]
                else            st[il * 72 + cl] = hv;   // [n][d]
            }
    __syncthreads();
    if (which < 2) {
        ushort_t* dst = (which == 0) ? qs : ks;
#pragma unroll
        for (int s = tid; s < 512; s += 256) {
            int rr = s >> 3, dc = (s & 7) * 8;
            *(short8*)&dst[(hidx * 2048 + n0 + rr) * 64 + dc] = *(const short8*)&st[rr * 72 + dc];
        }
    } else {
#pragma unroll
        for (int s = tid; s < 512; s += 256) {
            int d = s >> 3, nc = (s & 7) * 8;
            *(short8*)&vt[(hidx * 64 + d) * 2048 + n0 + nc] = *(const short8*)&st[d * 72 + nc];
        }
    }
}

// ---------------------------------------------------------------- K2: single-pass fused attention
// Software-pipelined: K prefetched one j-tile ahead (regs), V issued at premix
// start, U double-buffered -> ONE raw barrier per j-tile (lgkmcnt drain only,
// global prefetches stay in flight across it).
__global__ __launch_bounds__(512, 2) void k_attn(const ushort_t* __restrict__ qs,
                                                 const ushort_t* __restrict__ ks,
                                                 const ushort_t* __restrict__ vt,
                                                 const float* __restrict__ w_pre,
                                                 const float* __restrict__ w_post,
                                                 const ushort_t* __restrict__ wot,
                                                 const float* __restrict__ bias,
                                                 float* __restrict__ out) {
    __shared__ __align__(16) ushort_t qlds[8 * 16 * 72];     // q tiles, 8 heads x 16 rows
    __shared__ __align__(16) ushort_t U[2][8 * 16 * 136];    // unnorm P, double-buffered
    __shared__ __align__(16) ushort_t oline[16 * 520];       // attention out rows (16 x 512)
    __shared__ float wbuf[128];                              // fp32 w_pre | w_post
    __shared__ float lred[8][8][16];                         // per-wave l partials
    __shared__ float linv[8][16];                            // 1 / l_g[i]
    const int tid = threadIdx.x, lane = tid & 63, wv = tid >> 6;
    const int col = lane & 15, quad = lane >> 4;
    const int b = blockIdx.y, n0 = blockIdx.x * 16;
    const int e = wv;  // wave's output head

    if (tid < 64) wbuf[tid] = w_pre[tid];
    else if (tid < 128) wbuf[tid] = w_post[tid - 64];
    for (int c = tid; c < 1024; c += 512) {
        int hh = c >> 7, rem = c & 127, ii = rem >> 3, dc = (rem & 7) * 8;
        *(short8*)&qlds[(hh * 16 + ii) * 72 + dc] =
            *(const short8*)&qs[((b * 8 + hh) * 2048 + n0 + ii) * 64 + dc];
    }

    floatx4 Lacc[8];
    floatx4 Oa[8][4];
#pragma unroll
    for (int g = 0; g < 8; g++) {
        Lacc[g] = (floatx4){0.f, 0.f, 0.f, 0.f};
#pragma unroll
        for (int nt = 0; nt < 4; nt++) Oa[g][nt] = (floatx4){0.f, 0.f, 0.f, 0.f};
    }

    // ---- prologue: K prefetch for jt=0
    short8 kb0[8], kb1[8];
    {
        const int jw = wv * 16;
#pragma unroll
        for (int h = 0; h < 8; h++) {
            const ushort_t* kp = &ks[((b * 8 + h) * 2048 + jw + col) * 64 + quad * 8];
            kb0[h] = *(const short8*)&kp[0];
            kb1[h] = *(const short8*)&kp[32];
        }
    }
    __syncthreads();  // qlds + wbuf visible (drains prologue loads too; one-time)

    int cur = 0;
    for (int jt = 0; jt < 16; jt++) {
        // ---- QK for all 8 heads (K regs prefetched last iteration)
        floatx4 S[8];
#pragma unroll
        for (int h = 0; h < 8; h++) {
            const ushort_t* qb = &qlds[(h * 16 + col) * 72 + quad * 8];
            short8 a0 = *(const short8*)&qb[0];
            short8 a1 = *(const short8*)&qb[32];
            floatx4 a = (floatx4){0.f, 0.f, 0.f, 0.f};
            a = MFMA16(a0, kb0[h], a);
            a = MFMA16(a1, kb1[h], a);
            S[h] = a;
        }
        // ---- issue V loads for THIS jt (consumed after the barrier in PV)
        short8 vbr[16];
        const int j0 = jt * 128;
#pragma unroll
        for (int k2 = 0; k2 < 4; k2++)
#pragma unroll
            for (int nt = 0; nt < 4; nt++)
                vbr[k2 * 4 + nt] = *(const short8*)&vt[((b * 8 + e) * 64 + nt * 16 + col) * 2048 +
                                                       j0 + k2 * 32 + quad * 8];
        // ---- issue K loads for NEXT jt (consumed at next loop top)
        if (jt < 15) {
            const int jw = (jt + 1) * 128 + wv * 16;
#pragma unroll
            for (int h = 0; h < 8; h++) {
                const ushort_t* kp = &ks[((b * 8 + h) * 2048 + jw + col) * 64 + quad * 8];
                kb0[h] = *(const short8*)&kp[0];
                kb1[h] = *(const short8*)&kp[32];
            }
        }
        // ---- premix + exp (no shift) + l accumulate + U write (A-layout)
        ushort_t* Uc = U[cur];
#pragma unroll
        for (int g = 0; g < 8; g++) {
            floatx4 w0 = *(const floatx4*)&wbuf[g * 8];
            floatx4 w1 = *(const floatx4*)&wbuf[g * 8 + 4];
            floatx4 s4 = (floatx4){0.f, 0.f, 0.f, 0.f};
#pragma unroll
            for (int h = 0; h < 4; h++) s4 = fma4(w0[h], S[h], s4);
#pragma unroll
            for (int h = 0; h < 4; h++) s4 = fma4(w1[h], S[h + 4], s4);
            floatx4 u4;
            u4[0] = __expf(s4[0]);
            u4[1] = __expf(s4[1]);
            u4[2] = __expf(s4[2]);
            u4[3] = __expf(s4[3]);
            Lacc[g] += u4;
#pragma unroll
            for (int r = 0; r < 4; r++)
                Uc[(g * 16 + quad * 4 + r) * 136 + wv * 16 + col] = f2bf(u4[r]);
        }
        // ---- single barrier per tile: drain LDS writes only, keep global
        //      prefetches (vmcnt) in flight across the barrier.
        asm volatile("s_waitcnt lgkmcnt(0)\n\ts_barrier" ::: "memory");
        // ---- PV: O'_{e,g} += U_g @ V_e over this 128-j tile
#pragma unroll
        for (int k2 = 0; k2 < 4; k2++) {
            short8 af[8];
#pragma unroll
            for (int g = 0; g < 8; g++)
                af[g] = *(const short8*)&Uc[(g * 16 + col) * 136 + k2 * 32 + quad * 8];
#pragma unroll
            for (int g = 0; g < 8; g++)
#pragma unroll
                for (int nt = 0; nt < 4; nt++)
                    Oa[g][nt] = MFMA16(af[g], vbr[k2 * 4 + nt], Oa[g][nt]);
        }
        cur ^= 1;
        // no second barrier: next premix writes U[cur^1]; reuse of U[cur] at
        // jt+2 is ordered by the jt+1 barrier.
    }

    // ---- reduce l across 16 cols in-wave, then across waves
#pragma unroll
    for (int g = 0; g < 8; g++)
#pragma unroll
        for (int r = 0; r < 4; r++) {
            float v = Lacc[g][r];
            v += __shfl_xor(v, 1, 64);
            v += __shfl_xor(v, 2, 64);
            v += __shfl_xor(v, 4, 64);
            v += __shfl_xor(v, 8, 64);
            if (col == 0) lred[wv][g][quad * 4 + r] = v;
        }
    __syncthreads();
    if (tid < 128) {
        int g = tid >> 4, ii = tid & 15;
        float l = 0.f;
#pragma unroll
        for (int w2 = 0; w2 < 8; w2++) l += lred[w2][g][ii];
        linv[g][ii] = 1.0f / l;
    }
    __syncthreads();
    // ---- epilogue combine: O_e = sum_g wq[e,g]/l_g[i] * O'_{e,g}
    float coef[8][4];
#pragma unroll
    for (int g = 0; g < 8; g++) {
        float wqe = wbuf[64 + e * 8 + g];
#pragma unroll
        for (int r = 0; r < 4; r++) coef[g][r] = wqe * linv[g][quad * 4 + r];
    }
#pragma unroll
    for (int nt = 0; nt < 4; nt++)
#pragma unroll
        for (int r = 0; r < 4; r++) {
            float o = 0.f;
#pragma unroll
            for (int g = 0; g < 8; g++) o = fmaf(coef[g][r], Oa[g][nt][r], o);
            oline[(quad * 4 + r) * 520 + e * 64 + nt * 16 + col] = f2bf(o);
        }
    __syncthreads();
    // ---- fused output projection: out[16 x 512] = oline @ w_out + bias
#pragma unroll
    for (int nt = 0; nt < 4; nt++) {
        floatx4 acc = (floatx4){0.f, 0.f, 0.f, 0.f};
        const int c = wv * 64 + nt * 16 + col;
#pragma unroll
        for (int k2 = 0; k2 < 16; k2++) {
            short8 af = *(const short8*)&oline[col * 520 + k2 * 32 + quad * 8];
            short8 bf = *(const short8*)&wot[c * 512 + k2 * 32 + quad * 8];
            acc = MFMA16(af, bf, acc);
        }
        float bz = bias[c];
#pragma unroll
        for (int r = 0; r < 4; r++)
            out[(b * 2048 + n0 + quad * 4 + r) * 512 + c] = acc[r] + bz;
    }
}

// ---------------------------------------------------------------- launch
extern "C" void kernel_launch(void* const* d_in, const int* in_sizes, int n_in,
                              void* d_out, int out_size, void* d_ws, size_t ws_size,
                              hipStream_t stream) {
    const float* x = (const float*)d_in[0];
    const float* w_qkv = (const float*)d_in[1];
    const float* w_pre = (const float*)d_in[2];
    const float* w_post = (const float*)d_in[3];
    const float* w_out = (const float*)d_in[4];
    const float* b_out = (const float*)d_in[5];
    char* ws = (char*)d_ws;
    ushort_t* qs = (ushort_t*)(ws);                            // 4 MB  [b,h,n,d] (pre-scaled)
    ushort_t* ks = (ushort_t*)(ws + (4u << 20));               // 4 MB  [b,h,n,d]
    ushort_t* vt = (ushort_t*)(ws + (8u << 20));               // 4 MB  [b,h,d,n]
    ushort_t* xb = (ushort_t*)(ws + (12u << 20));              // 4 MB  x in bf16
    ushort_t* wt = (ushort_t*)(ws + (16u << 20));              // 1.5 MB w_qkv^T bf16
    ushort_t* wot = (ushort_t*)(ws + (16u << 20) + 1572864u);  // 0.5 MB w_out^T bf16
    float* out = (float*)d_out;

    k_cvt<<<dim3(2048), dim3(256), 0, stream>>>((const floatx4*)x, (short4v*)xb, 524288);
    k_transpose_cvt<<<dim3(48, 16), dim3(256), 0, stream>>>(w_qkv, wt, 512, 1536);
    k_transpose_cvt<<<dim3(16, 16), dim3(256), 0, stream>>>(w_out, wot, 512, 512);
    k_qkv<<<dim3(24, 64), dim3(256), 0, stream>>>(xb, wt, qs, ks, vt);
    k_attn<<<dim3(128, 2), dim3(512), 0, stream>>>(qs, ks, vt, w_pre, w_post, wot, b_out, out);
}

// Round 2
// 343.482 us; speedup vs baseline: 1.4872x; 1.4872x over previous
//
#include <hip/hip_runtime.h>
#include <hip/hip_bf16.h>

typedef unsigned short ushort_t;
typedef __attribute__((ext_vector_type(8))) short short8;
typedef __attribute__((ext_vector_type(4))) short short4v;
typedef __attribute__((ext_vector_type(4))) float floatx4;

#define MFMA16(a, b, c) __builtin_amdgcn_mfma_f32_16x16x32_bf16(a, b, c, 0, 0, 0)

__device__ __forceinline__ float bf2f(ushort_t u) {
    unsigned int v = ((unsigned int)u) << 16;
    return __int_as_float((int)v);
}
__device__ __forceinline__ ushort_t f2bf(float f) {
    unsigned int x = (unsigned int)__float_as_int(f);
    unsigned int r = (x + 0x7FFFu + ((x >> 16) & 1u)) >> 16;
    return (ushort_t)r;
}
__device__ __forceinline__ floatx4 fma4(float a, floatx4 b, floatx4 c) {
    c[0] = fmaf(a, b[0], c[0]);
    c[1] = fmaf(a, b[1], c[1]);
    c[2] = fmaf(a, b[2], c[2]);
    c[3] = fmaf(a, b[3], c[3]);
    return c;
}

// ---------------------------------------------------------------- fp32 -> bf16 convert
__global__ __launch_bounds__(256) void k_cvt(const floatx4* __restrict__ src,
                                             short4v* __restrict__ dst, int n4) {
    int i = blockIdx.x * 256 + threadIdx.x;
    if (i < n4) {
        floatx4 v = src[i];
        short4v o;
        o[0] = (short)f2bf(v[0]);
        o[1] = (short)f2bf(v[1]);
        o[2] = (short)f2bf(v[2]);
        o[3] = (short)f2bf(v[3]);
        dst[i] = o;
    }
}

// ---------------------------------------------------------------- fp32 transpose -> bf16
__global__ __launch_bounds__(256) void k_transpose_cvt(const float* __restrict__ src,
                                                       ushort_t* __restrict__ dst, int R, int C) {
    __shared__ float t[32][33];
    int tx = threadIdx.x & 31, ty = threadIdx.x >> 5;
    int r0 = blockIdx.y * 32, c0 = blockIdx.x * 32;
    for (int y = ty; y < 32; y += 8) t[y][tx] = src[(r0 + y) * C + c0 + tx];
    __syncthreads();
    for (int y = ty; y < 32; y += 8) dst[(c0 + y) * R + r0 + tx] = f2bf(t[tx][y]);
}

// ---------------------------------------------------------------- K1: qkv = x @ w_qkv, scatter q/k/vT
__global__ __launch_bounds__(256) void k_qkv(const ushort_t* __restrict__ x,
                                             const ushort_t* __restrict__ wt,
                                             ushort_t* __restrict__ qs,
                                             ushort_t* __restrict__ ks,
                                             ushort_t* __restrict__ vt) {
    __shared__ __align__(16) ushort_t st[64 * 72];
    const int tid = threadIdx.x, lane = tid & 63, wv = tid >> 6;
    const int col = lane & 15, quad = lane >> 4;
    const int row0 = blockIdx.y * 64 + (wv >> 1) * 32;
    const int c0 = blockIdx.x * 64 + (wv & 1) * 32;
    const int which = blockIdx.x >> 3, hh = blockIdx.x & 7;
    const int brow0 = blockIdx.y * 64;
    const int bb = brow0 >> 11, n0 = brow0 & 2047;
    const int hidx = bb * 8 + hh;
    floatx4 acc[2][2];
#pragma unroll
    for (int i = 0; i < 2; i++)
#pragma unroll
        for (int j = 0; j < 2; j++) acc[i][j] = (floatx4){0.f, 0.f, 0.f, 0.f};
    for (int k0 = 0; k0 < 512; k0 += 32) {
        const int ko = k0 + quad * 8;
        short8 a0 = *(const short8*)&x[(row0 + col) * 512 + ko];
        short8 a1 = *(const short8*)&x[(row0 + 16 + col) * 512 + ko];
        short8 b0 = *(const short8*)&wt[(c0 + col) * 512 + ko];
        short8 b1 = *(const short8*)&wt[(c0 + 16 + col) * 512 + ko];
        acc[0][0] = MFMA16(a0, b0, acc[0][0]);
        acc[0][1] = MFMA16(a0, b1, acc[0][1]);
        acc[1][0] = MFMA16(a1, b0, acc[1][0]);
        acc[1][1] = MFMA16(a1, b1, acc[1][1]);
    }
    const float qscale = (which == 0) ? 0.125f : 1.0f;  // fold SCALE into q
#pragma unroll
    for (int i = 0; i < 2; i++)
#pragma unroll
        for (int j = 0; j < 2; j++)
#pragma unroll
            for (int r = 0; r < 4; r++) {
                int il = (wv >> 1) * 32 + i * 16 + quad * 4 + r;
                int cl = (wv & 1) * 32 + j * 16 + col;
                ushort_t hv = f2bf(acc[i][j][r] * qscale);
                if (which == 2) st[cl * 72 + il] = hv;   // transposed: [d][n]
                else            st[il * 72 + cl] = hv;   // [n][d]
            }
    __syncthreads();
    if (which < 2) {
        ushort_t* dst = (which == 0) ? qs : ks;
#pragma unroll
        for (int s = tid; s < 512; s += 256) {
            int rr = s >> 3, dc = (s & 7) * 8;
            *(short8*)&dst[(hidx * 2048 + n0 + rr) * 64 + dc] = *(const short8*)&st[rr * 72 + dc];
        }
    } else {
#pragma unroll
        for (int s = tid; s < 512; s += 256) {
            int d = s >> 3, nc = (s & 7) * 8;
            *(short8*)&vt[(hidx * 64 + d) * 2048 + n0 + nc] = *(const short8*)&st[d * 72 + nc];
        }
    }
}

// ---------------------------------------------------------------- K2: two-pass fused attention
// Pass A: streaming QK+premix+exp -> l_g[i] only (no LDS, no barriers, K prefetched).
// Pass B: recompute QK, normalize by 1/l_g and apply w_post mix IN-REGISTER, write
// final mixed attention A_e (bf16) to LDS, PV with ONE accumulator (16 regs).
// Register prefetch of K and V now fits the 256-reg budget -> no spills.
__global__ __launch_bounds__(512, 2) void k_attn(const ushort_t* __restrict__ qs,
                                                 const ushort_t* __restrict__ ks,
                                                 const ushort_t* __restrict__ vt,
                                                 const float* __restrict__ w_pre,
                                                 const float* __restrict__ w_post,
                                                 const ushort_t* __restrict__ wot,
                                                 const float* __restrict__ bias,
                                                 float* __restrict__ out) {
    __shared__ __align__(16) ushort_t qlds[8 * 16 * 72];   // q tiles, 8 heads x 16 rows
    __shared__ __align__(16) ushort_t A[2][8 * 16 * 136];  // mixed attn, double-buffered
    __shared__ __align__(16) ushort_t oline[16 * 520];     // attention out rows (16 x 512)
    __shared__ __align__(16) float wbuf[128];              // fp32 w_pre | w_post
    __shared__ float lred[8][8][16];                       // per-wave l partials
    __shared__ __align__(16) float linv[8][16];            // 1 / l_g[i]
    const int tid = threadIdx.x, lane = tid & 63, wv = tid >> 6;
    const int col = lane & 15, quad = lane >> 4;
    const int b = blockIdx.y, n0 = blockIdx.x * 16;
    const int e = wv;  // wave's output head

    if (tid < 64) wbuf[tid] = w_pre[tid];
    else if (tid < 128) wbuf[tid] = w_post[tid - 64];
    for (int c = tid; c < 1024; c += 512) {
        int hh = c >> 7, rem = c & 127, ii = rem >> 3, dc = (rem & 7) * 8;
        *(short8*)&qlds[(hh * 16 + ii) * 72 + dc] =
            *(const short8*)&qs[((b * 8 + hh) * 2048 + n0 + ii) * 64 + dc];
    }

    // ================= Pass A: denominators l_g[i] =================
    short8 kb0[8], kb1[8];
#pragma unroll
    for (int h = 0; h < 8; h++) {  // prefetch jt=0
        const ushort_t* kp = &ks[((b * 8 + h) * 2048 + wv * 16 + col) * 64 + quad * 8];
        kb0[h] = *(const short8*)&kp[0];
        kb1[h] = *(const short8*)&kp[32];
    }
    __syncthreads();  // qlds + wbuf visible

    short8 qa0[8], qa1[8];  // q fragments hoisted for pass A
#pragma unroll
    for (int h = 0; h < 8; h++) {
        const ushort_t* qb = &qlds[(h * 16 + col) * 72 + quad * 8];
        qa0[h] = *(const short8*)&qb[0];
        qa1[h] = *(const short8*)&qb[32];
    }

    floatx4 Lacc[8];
#pragma unroll
    for (int g = 0; g < 8; g++) Lacc[g] = (floatx4){0.f, 0.f, 0.f, 0.f};

    for (int jt = 0; jt < 16; jt++) {
        floatx4 S[8];
#pragma unroll
        for (int h = 0; h < 8; h++) {
            floatx4 a = (floatx4){0.f, 0.f, 0.f, 0.f};
            a = MFMA16(qa0[h], kb0[h], a);
            a = MFMA16(qa1[h], kb1[h], a);
            S[h] = a;
        }
        if (jt < 15) {  // prefetch K for jt+1 (latency hides under premix)
            const int jw = (jt + 1) * 128 + wv * 16;
#pragma unroll
            for (int h = 0; h < 8; h++) {
                const ushort_t* kp = &ks[((b * 8 + h) * 2048 + jw + col) * 64 + quad * 8];
                kb0[h] = *(const short8*)&kp[0];
                kb1[h] = *(const short8*)&kp[32];
            }
        }
#pragma unroll
        for (int g = 0; g < 8; g++) {
            floatx4 w0 = *(const floatx4*)&wbuf[g * 8];
            floatx4 w1 = *(const floatx4*)&wbuf[g * 8 + 4];
            floatx4 s4 = (floatx4){0.f, 0.f, 0.f, 0.f};
#pragma unroll
            for (int h = 0; h < 4; h++) s4 = fma4(w0[h], S[h], s4);
#pragma unroll
            for (int h = 0; h < 4; h++) s4 = fma4(w1[h], S[h + 4], s4);
            floatx4 u4;
            u4[0] = __expf(s4[0]);
            u4[1] = __expf(s4[1]);
            u4[2] = __expf(s4[2]);
            u4[3] = __expf(s4[3]);
            Lacc[g] += u4;
        }
    }

    // ---- reduce l across 16 cols in-wave, then across waves
#pragma unroll
    for (int g = 0; g < 8; g++)
#pragma unroll
        for (int r = 0; r < 4; r++) {
            float v = Lacc[g][r];
            v += __shfl_xor(v, 1, 64);
            v += __shfl_xor(v, 2, 64);
            v += __shfl_xor(v, 4, 64);
            v += __shfl_xor(v, 8, 64);
            if (col == 0) lred[wv][g][quad * 4 + r] = v;
        }
    __syncthreads();
    if (tid < 128) {
        int g = tid >> 4, ii = tid & 15;
        float l = 0.f;
#pragma unroll
        for (int w2 = 0; w2 < 8; w2++) l += lred[w2][g][ii];
        linv[g][ii] = 1.0f / l;
    }
    __syncthreads();

    // ================= Pass B: normalized+mixed attention, PV =================
#pragma unroll
    for (int h = 0; h < 8; h++) {  // re-prefetch K jt=0 (L2-hot)
        const ushort_t* kp = &ks[((b * 8 + h) * 2048 + wv * 16 + col) * 64 + quad * 8];
        kb0[h] = *(const short8*)&kp[0];
        kb1[h] = *(const short8*)&kp[32];
    }
    short8 vbr[16];
#pragma unroll
    for (int k2 = 0; k2 < 4; k2++)  // prefetch V jt=0
#pragma unroll
        for (int nt = 0; nt < 4; nt++)
            vbr[k2 * 4 + nt] = *(const short8*)&vt[((b * 8 + e) * 64 + nt * 16 + col) * 2048 +
                                                   k2 * 32 + quad * 8];
    floatx4 Oa[4];
#pragma unroll
    for (int nt = 0; nt < 4; nt++) Oa[nt] = (floatx4){0.f, 0.f, 0.f, 0.f};

    int cur = 0;
    for (int jt = 0; jt < 16; jt++) {
        // ---- QK (q re-read from LDS to keep register peak low)
        floatx4 S[8];
#pragma unroll
        for (int h = 0; h < 8; h++) {
            const ushort_t* qb = &qlds[(h * 16 + col) * 72 + quad * 8];
            short8 a0 = *(const short8*)&qb[0];
            short8 a1 = *(const short8*)&qb[32];
            floatx4 a = (floatx4){0.f, 0.f, 0.f, 0.f};
            a = MFMA16(a0, kb0[h], a);
            a = MFMA16(a1, kb1[h], a);
            S[h] = a;
        }
        if (jt < 15) {  // prefetch K for jt+1
            const int jw = (jt + 1) * 128 + wv * 16;
#pragma unroll
            for (int h = 0; h < 8; h++) {
                const ushort_t* kp = &ks[((b * 8 + h) * 2048 + jw + col) * 64 + quad * 8];
                kb0[h] = *(const short8*)&kp[0];
                kb1[h] = *(const short8*)&kp[32];
            }
        }
        // ---- premix + exp + normalize (1/l_g) -> Ug
        floatx4 Ug[8];
#pragma unroll
        for (int g = 0; g < 8; g++) {
            floatx4 w0 = *(const floatx4*)&wbuf[g * 8];
            floatx4 w1 = *(const floatx4*)&wbuf[g * 8 + 4];
            floatx4 s4 = (floatx4){0.f, 0.f, 0.f, 0.f};
#pragma unroll
            for (int h = 0; h < 4; h++) s4 = fma4(w0[h], S[h], s4);
#pragma unroll
            for (int h = 0; h < 4; h++) s4 = fma4(w1[h], S[h + 4], s4);
            floatx4 lg = *(const floatx4*)&linv[g][quad * 4];
            floatx4 u4;
            u4[0] = __expf(s4[0]) * lg[0];
            u4[1] = __expf(s4[1]) * lg[1];
            u4[2] = __expf(s4[2]) * lg[2];
            u4[3] = __expf(s4[3]) * lg[3];
            Ug[g] = u4;
        }
        // ---- post-mix: A_e = sum_g w_post[e,g] * Ug  -> LDS (bf16, A-operand layout)
        ushort_t* Ac = A[cur];
#pragma unroll
        for (int e2 = 0; e2 < 8; e2++) {
            floatx4 wqa = *(const floatx4*)&wbuf[64 + e2 * 8];
            floatx4 wqb = *(const floatx4*)&wbuf[64 + e2 * 8 + 4];
            floatx4 a4 = (floatx4){0.f, 0.f, 0.f, 0.f};
#pragma unroll
            for (int g = 0; g < 4; g++) a4 = fma4(wqa[g], Ug[g], a4);
#pragma unroll
            for (int g = 0; g < 4; g++) a4 = fma4(wqb[g], Ug[g + 4], a4);
#pragma unroll
            for (int r = 0; r < 4; r++)
                Ac[(e2 * 16 + quad * 4 + r) * 136 + wv * 16 + col] = f2bf(a4[r]);
        }
        // ---- single barrier per tile: drain LDS writes only; global prefetches
        //      (K jt+1, V jt) stay in flight across it.
        asm volatile("s_waitcnt lgkmcnt(0)\n\ts_barrier" ::: "memory");
        // ---- PV: O_e += A_e @ V_e over this 128-j tile (one accumulator!)
#pragma unroll
        for (int k2 = 0; k2 < 4; k2++) {
            short8 af = *(const short8*)&Ac[(e * 16 + col) * 136 + k2 * 32 + quad * 8];
#pragma unroll
            for (int nt = 0; nt < 4; nt++) Oa[nt] = MFMA16(af, vbr[k2 * 4 + nt], Oa[nt]);
        }
        if (jt < 15) {  // prefetch V for jt+1 (hides under next QK+premix)
            const int j0 = (jt + 1) * 128;
#pragma unroll
            for (int k2 = 0; k2 < 4; k2++)
#pragma unroll
                for (int nt = 0; nt < 4; nt++)
                    vbr[k2 * 4 + nt] =
                        *(const short8*)&vt[((b * 8 + e) * 64 + nt * 16 + col) * 2048 + j0 +
                                            k2 * 32 + quad * 8];
        }
        cur ^= 1;
        // no second barrier: next tile writes A[cur^1]; reuse of A[cur] at jt+2
        // is ordered by the jt+1 barrier (lgkmcnt(0) drains this wave's PV reads).
    }

    // ---- epilogue: O already normalized+mixed -> oline, then output projection
#pragma unroll
    for (int nt = 0; nt < 4; nt++)
#pragma unroll
        for (int r = 0; r < 4; r++)
            oline[(quad * 4 + r) * 520 + e * 64 + nt * 16 + col] = f2bf(Oa[nt][r]);
    __syncthreads();
#pragma unroll
    for (int nt = 0; nt < 4; nt++) {
        floatx4 acc = (floatx4){0.f, 0.f, 0.f, 0.f};
        const int c = wv * 64 + nt * 16 + col;
#pragma unroll
        for (int k2 = 0; k2 < 16; k2++) {
            short8 af = *(const short8*)&oline[col * 520 + k2 * 32 + quad * 8];
            short8 bf = *(const short8*)&wot[c * 512 + k2 * 32 + quad * 8];
            acc = MFMA16(af, bf, acc);
        }
        float bz = bias[c];
#pragma unroll
        for (int r = 0; r < 4; r++)
            out[(b * 2048 + n0 + quad * 4 + r) * 512 + c] = acc[r] + bz;
    }
}

// ---------------------------------------------------------------- launch
extern "C" void kernel_launch(void* const* d_in, const int* in_sizes, int n_in,
                              void* d_out, int out_size, void* d_ws, size_t ws_size,
                              hipStream_t stream) {
    const float* x = (const float*)d_in[0];
    const float* w_qkv = (const float*)d_in[1];
    const float* w_pre = (const float*)d_in[2];
    const float* w_post = (const float*)d_in[3];
    const float* w_out = (const float*)d_in[4];
    const float* b_out = (const float*)d_in[5];
    char* ws = (char*)d_ws;
    ushort_t* qs = (ushort_t*)(ws);                            // 4 MB  [b,h,n,d] (pre-scaled)
    ushort_t* ks = (ushort_t*)(ws + (4u << 20));               // 4 MB  [b,h,n,d]
    ushort_t* vt = (ushort_t*)(ws + (8u << 20));               // 4 MB  [b,h,d,n]
    ushort_t* xb = (ushort_t*)(ws + (12u << 20));              // 4 MB  x in bf16
    ushort_t* wt = (ushort_t*)(ws + (16u << 20));              // 1.5 MB w_qkv^T bf16
    ushort_t* wot = (ushort_t*)(ws + (16u << 20) + 1572864u);  // 0.5 MB w_out^T bf16
    float* out = (float*)d_out;

    k_cvt<<<dim3(2048), dim3(256), 0, stream>>>((const floatx4*)x, (short4v*)xb, 524288);
    k_transpose_cvt<<<dim3(48, 16), dim3(256), 0, stream>>>(w_qkv, wt, 512, 1536);
    k_transpose_cvt<<<dim3(16, 16), dim3(256), 0, stream>>>(w_out, wot, 512, 512);
    k_qkv<<<dim3(24, 64), dim3(256), 0, stream>>>(xb, wt, qs, ks, vt);
    k_attn<<<dim3(128, 2), dim3(512), 0, stream>>>(qs, ks, vt, w_pre, w_post, wot, b_out, out);
}